// Round 1
// baseline (3288.659 us; speedup 1.0000x reference)
//
#include <hip/hip_runtime.h>
#include <hip/hip_bf16.h>

// BRC layer: 3 batched GEMMs (x @ U^T) + elementwise-independent bistable scan.
// Round 3: software-pipelined launch fusion. scan(k) ∥ gemm(k+1) ∥ cvt(k+2) in
//   ONE grid (no inter-block deps: different chunks, double-buffered planes).
//   Scan blocks dispatched first (longest latency chain), 4-step-deep prefetch
//   (static-indexed regs), nontemporal output stores.
// Numerics identical to round 2 (split-fp16 Markidis GEMM, expf-based gates):
//   absmax must stay 0.0146.
// ws: [xhi0 16.8][xlo0 16.8][xhi1 16.8][xlo1 16.8][Uhi .75][Ulo .75]
//     [buf0 201][buf1 201][h 256K]  ~472 MB (ws is 2 GiB per poison fill)

typedef _Float16 half8 __attribute__((ext_vector_type(8)));
typedef float    f32x4 __attribute__((ext_vector_type(4)));

#define SEQ   2048
#define BATCH 128
#define INP   256
#define HID   512
#define CHUNK_T 256
#define NCHUNK  8
#define MLOC  (CHUNK_T * BATCH)        // 32768 rows per chunk
#define BJ    (BATCH * HID)            // 65536 recurrence strands

#define NS_BLK 256                     // scan blocks (1 per CU)
#define NG_BLK 3072                    // gemm blocks (256 m-tiles x 12 n-tiles)
#define NC_BLK 512                     // cvt blocks
#define TOT_BLK (NS_BLK + NG_BLK + NC_BLK)

// ---------------- fp32 -> (fp16 hi, fp16 lo) split, 8 elems/thread/iter -----
__device__ __forceinline__ void cvt_body(
    const float* __restrict__ src, _Float16* __restrict__ hi,
    _Float16* __restrict__ lo, int n8, int i, int stride)
{
    for (; i < n8; i += stride) {
        f32x4 a = ((const f32x4*)src)[2 * i];
        f32x4 b = ((const f32x4*)src)[2 * i + 1];
        half8 h, l;
#pragma unroll
        for (int k = 0; k < 4; ++k) {
            _Float16 hh = (_Float16)a[k];
            h[k] = hh; l[k] = (_Float16)(a[k] - (float)hh);
        }
#pragma unroll
        for (int k = 0; k < 4; ++k) {
            _Float16 hh = (_Float16)b[k];
            h[4 + k] = hh; l[4 + k] = (_Float16)(b[k] - (float)hh);
        }
        ((half8*)hi)[i] = h;
        ((half8*)lo)[i] = l;
    }
}

__global__ __launch_bounds__(256) void cvt_split(
    const float* __restrict__ src, _Float16* __restrict__ hi,
    _Float16* __restrict__ lo, int n8)
{
    cvt_body(src, hi, lo, n8,
             blockIdx.x * blockDim.x + threadIdx.x, gridDim.x * blockDim.x);
}

// ---------------- async 16B global->LDS ----------------
__device__ __forceinline__ void llds16(const void* g, void* l)
{
    __builtin_amdgcn_global_load_lds(
        (const __attribute__((address_space(1))) unsigned int*)g,
        (__attribute__((address_space(3))) unsigned int*)l,
        16, 0, 0);
}

// ---------------- GEMM: C[m, g, j] = sum_k A[m,k] * B[g*512+j, k] -----------
// A planes: (MLOC x 256) fp16.  B planes: (1536 x 256) fp16 = U_c|U_a|U_h rows.
// C: interleaved (MLOC x 512 x 3) fp32: addr = m*1536 + j*3 + g.
// Block: 256 thr = 4 waves; tile 128(M) x 128(N); K=256 in 4 steps of 64.
// LDS slot(r,cg) = r*8 + (cg ^ (r&7)); swizzle applied on the GLOBAL side so
// global_load_lds (wave-uniform base + lane*16) lands each lane correctly.
__device__ __forceinline__ void gemm_body(int bid,
    const _Float16* __restrict__ Ah, const _Float16* __restrict__ Al,
    const _Float16* __restrict__ Bh, const _Float16* __restrict__ Bl,
    float* __restrict__ C,
    _Float16* AsH, _Float16* AsL, _Float16* BsH, _Float16* BsL)
{
    const int tid  = threadIdx.x;
    const int lane = tid & 63;
    const int wv   = tid >> 6;       // wave 0..3
    const int quad = lane >> 4;      // 0..3
    const int l16  = lane & 15;
    const int m0   = (bid & 255) * 128;   // row tile within chunk
    const int n0   = (bid >> 8) * 128;    // col tile within 1536
    const int wm   = (wv >> 1) * 64;      // wave quadrant
    const int wn   = (wv & 1) * 64;

    f32x4 acc[4][4];
    const f32x4 zero = {0.0f, 0.0f, 0.0f, 0.0f};
#pragma unroll
    for (int i = 0; i < 4; ++i)
#pragma unroll
        for (int j = 0; j < 4; ++j) acc[i][j] = zero;

    for (int ko = 0; ko < 4; ++ko) {
        const int k0 = ko * 64;
        __syncthreads();
#pragma unroll
        for (int i = 0; i < 4; ++i) {
            const int s  = i * 256 + tid;
            const int r  = s >> 3;
            const int cg = (s & 7) ^ (r & 7);
            const size_t ga = (size_t)(m0 + r) * INP + k0 + cg * 8;
            const size_t gb = (size_t)(n0 + r) * INP + k0 + cg * 8;
            const size_t dst = (size_t)(i * 256 + wv * 64) * 16;
            llds16(Ah + ga, (char*)AsH + dst);
            llds16(Al + ga, (char*)AsL + dst);
            llds16(Bh + gb, (char*)BsH + dst);
            llds16(Bl + gb, (char*)BsL + dst);
        }
        __syncthreads();
#pragma unroll
        for (int ks = 0; ks < 2; ++ks) {
            const int cgk = ks * 4 + quad;   // 16B group index within 8
            half8 ah[4], al[4], bh[4], bl[4];
#pragma unroll
            for (int mf = 0; mf < 4; ++mf) {
                const int row = wm + mf * 16 + l16;
                const size_t off = (size_t)(row * 8 + (cgk ^ (row & 7))) * 8;
                ah[mf] = *(const half8*)(AsH + off);
                al[mf] = *(const half8*)(AsL + off);
            }
#pragma unroll
            for (int nf = 0; nf < 4; ++nf) {
                const int row = wn + nf * 16 + l16;
                const size_t off = (size_t)(row * 8 + (cgk ^ (row & 7))) * 8;
                bh[nf] = *(const half8*)(BsH + off);
                bl[nf] = *(const half8*)(BsL + off);
            }
#pragma unroll
            for (int mf = 0; mf < 4; ++mf)
#pragma unroll
                for (int nf = 0; nf < 4; ++nf) {
                    acc[mf][nf] = __builtin_amdgcn_mfma_f32_16x16x32_f16(
                        ah[mf], bh[nf], acc[mf][nf], 0, 0, 0);
                    acc[mf][nf] = __builtin_amdgcn_mfma_f32_16x16x32_f16(
                        ah[mf], bl[nf], acc[mf][nf], 0, 0, 0);
                    acc[mf][nf] = __builtin_amdgcn_mfma_f32_16x16x32_f16(
                        al[mf], bh[nf], acc[mf][nf], 0, 0, 0);
                }
        }
    }

    // epilogue: D frag layout col=lane&15, row=quad*4+reg (m89/m91 verified)
    const int g   = n0 >> 9;        // which matrix (c/a/h)
    const int nIn = n0 & 511;       // col base within matrix
#pragma unroll
    for (int mf = 0; mf < 4; ++mf)
#pragma unroll
        for (int nf = 0; nf < 4; ++nf)
#pragma unroll
            for (int r = 0; r < 4; ++r) {
                const int m = m0 + wm + mf * 16 + quad * 4 + r;
                const int j = nIn + wn + nf * 16 + l16;
                C[(size_t)m * 1536 + (size_t)j * 3 + g] = acc[mf][nf][r];
            }
}

// ---------------- recurrence scan: one thread per (b, j) ----------------
__device__ __forceinline__ float tanh_acc(float z)
{
    // 1 - 2/(exp(2z)+1): exact saturation at +/-inf, ~1e-7 abs error
    return 1.0f - 2.0f / (expf(2.0f * z) + 1.0f);
}

__device__ __forceinline__ void scan_body(int bid,
    const float* __restrict__ X,      // (MLOC, 512, 3) interleaved xc,xa,xh
    const float* __restrict__ h_in, float* __restrict__ h_out,
    const float* __restrict__ wc, const float* __restrict__ bc,
    const float* __restrict__ wa, const float* __restrict__ ba,
    float* __restrict__ out)
{
    const int bj = bid * 256 + threadIdx.x;   // 0..65535
    const int j  = bj & (HID - 1);
    float h = h_in[bj];
    const float wcj = wc[j], bcj = bc[j];
    const float waj = wa[j], baj = ba[j];

    size_t idx = (size_t)bj * 3;
    const size_t step = (size_t)BJ * 3;

    // 4-deep prefetch pipeline; static indexing via unroll-4 (keeps in VGPRs)
    float px[4][3];
#pragma unroll
    for (int i = 0; i < 4; ++i) {
        px[i][0] = X[idx]; px[i][1] = X[idx + 1]; px[i][2] = X[idx + 2];
        idx += step;
    }
#pragma unroll 4
    for (int t = 0; t < CHUNK_T; ++t) {
        const int s = t & 3;
        const float xc = px[s][0], xa = px[s][1], xh = px[s][2];
        if (t + 4 < CHUNK_T) {          // uniform branch
            px[s][0] = X[idx]; px[s][1] = X[idx + 1]; px[s][2] = X[idx + 2];
            idx += step;
        }
        const float c  = 1.0f / (1.0f + expf(-(xc + bcj + wcj * h)));
        const float a  = 1.0f + tanh_acc(xa + baj + waj * h);
        const float th = tanh_acc(xh + a * h);
        h = c * h + (1.0f - c) * th;
        // write-once 537MB stream: keep out of L2 (GEMM needs the locality)
        __builtin_nontemporal_store(h, &out[(size_t)t * BJ + bj]);
    }
    h_out[bj] = h;
}

// ---------------- fused pipeline step ----------------
// blocks [0,256): scan(k)      — longest critical path, dispatched first
// blocks [256,3328): gemm(k+1) — independent of scan(k) (other chunk buffer)
// blocks [3328,3840): cvt(k+2) — independent of both (other x-plane buffer)
__global__ __launch_bounds__(256) void fused_step(
    const float* __restrict__ scanX, const float* __restrict__ h_in,
    float* __restrict__ h_out, float* __restrict__ scanOut,
    const float* __restrict__ wc, const float* __restrict__ bc,
    const float* __restrict__ wa, const float* __restrict__ ba,
    const _Float16* __restrict__ gAh, const _Float16* __restrict__ gAl,
    const _Float16* __restrict__ gBh, const _Float16* __restrict__ gBl,
    float* __restrict__ gC,
    const float* __restrict__ cvtSrc, _Float16* __restrict__ cvtHi,
    _Float16* __restrict__ cvtLo)
{
    __shared__ __align__(16) _Float16 AsH[8192];  // 16 KB each (64 KB total)
    __shared__ __align__(16) _Float16 AsL[8192];
    __shared__ __align__(16) _Float16 BsH[8192];
    __shared__ __align__(16) _Float16 BsL[8192];

    int bid = blockIdx.x;
    if (bid < NS_BLK) {
        if (scanX)
            scan_body(bid, scanX, h_in, h_out, wc, bc, wa, ba, scanOut);
        return;
    }
    bid -= NS_BLK;
    if (bid < NG_BLK) {
        if (gAh)
            gemm_body(bid, gAh, gAl, gBh, gBl, gC, AsH, AsL, BsH, BsL);
        return;
    }
    bid -= NG_BLK;
    if (cvtSrc)
        cvt_body(cvtSrc, cvtHi, cvtLo, MLOC * INP / 8,
                 bid * 256 + (int)threadIdx.x, NC_BLK * 256);
}

// ---------------- launch ----------------
extern "C" void kernel_launch(void* const* d_in, const int* in_sizes, int n_in,
                              void* d_out, int out_size, void* d_ws, size_t ws_size,
                              hipStream_t stream)
{
    const float* x  = (const float*)d_in[0];
    const float* h0 = (const float*)d_in[1];
    const float* Uc = (const float*)d_in[2];
    const float* wc = (const float*)d_in[3];
    const float* bc = (const float*)d_in[4];
    const float* Ua = (const float*)d_in[5];
    const float* wa = (const float*)d_in[6];
    const float* ba = (const float*)d_in[7];
    const float* Uh = (const float*)d_in[8];
    float* out = (float*)d_out;

    char* ws = (char*)d_ws;
    const size_t XCH = (size_t)MLOC * INP;            // 8388608 halves/plane
    _Float16* xhiB[2]; _Float16* xloB[2];
    xhiB[0] = (_Float16*)ws;
    xloB[0] = xhiB[0] + XCH;
    xhiB[1] = xloB[0] + XCH;
    xloB[1] = xhiB[1] + XCH;
    _Float16* Uhi = xloB[1] + XCH;
    _Float16* Ulo = Uhi + (size_t)3 * HID * INP;
    float* bufB[2];
    bufB[0] = (float*)(Ulo + (size_t)3 * HID * INP);  // MLOC*1536 f32 each
    bufB[1] = bufB[0] + (size_t)MLOC * 1536;
    float* hstate = bufB[1] + (size_t)MLOC * 1536;    // 65536 f32

    // U splits (tiny, once)
    cvt_split<<<64, 256, 0, stream>>>(Uc, Uhi,                 Ulo,                 HID * INP / 8);
    cvt_split<<<64, 256, 0, stream>>>(Ua, Uhi + HID * INP,     Ulo + HID * INP,     HID * INP / 8);
    cvt_split<<<64, 256, 0, stream>>>(Uh, Uhi + 2 * HID * INP, Ulo + 2 * HID * INP, HID * INP / 8);
    // x chunk 0 split (prologue)
    cvt_split<<<4096, 256, 0, stream>>>(x, xhiB[0], xloB[0], MLOC * INP / 8);

    // pipeline: step k runs scan(k) ∥ gemm(k+1) ∥ cvt(k+2)
    for (int k = -1; k < NCHUNK; ++k) {
        const int kg = k + 1, kc = k + 2;

        const float* scanX = nullptr; const float* hin = nullptr;
        float* hout = nullptr; float* sout = nullptr;
        if (k >= 0) {
            scanX = bufB[k & 1];
            hin   = (k == 0) ? h0 : hstate;
            hout  = (k == NCHUNK - 1) ? (out + (size_t)SEQ * BJ) : hstate;
            sout  = out + (size_t)k * CHUNK_T * BJ;
        }

        const _Float16* gah = nullptr; const _Float16* gal = nullptr;
        float* gc = nullptr;
        if (kg < NCHUNK) {
            gah = xhiB[kg & 1]; gal = xloB[kg & 1]; gc = bufB[kg & 1];
        }

        const float* csrc = nullptr; _Float16* chi = nullptr; _Float16* clo = nullptr;
        if (kc < NCHUNK) {
            csrc = x + (size_t)kc * MLOC * INP;
            chi = xhiB[kc & 1]; clo = xloB[kc & 1];
        }

        fused_step<<<TOT_BLK, 256, 0, stream>>>(
            scanX, hin, hout, sout, wc, bc, wa, ba,
            gah, gal, Uhi, Ulo, gc, csrc, chi, clo);
    }
}